// Round 3
// baseline (333.172 us; speedup 1.0000x reference)
//
#include <hip/hip_runtime.h>
#include <math.h>

// Problem constants
#define BB 16
#define C1 256     // in/out channels of the block
#define CHD 128    // hidden channels
#define NN 4096    // H*W
#define INV_T (1.0f/16.0f)   // TEMPERATURE = sqrt(256) = 16

typedef _Float16 half8 __attribute__((ext_vector_type(8)));
typedef __attribute__((ext_vector_type(4))) float f32x4;
typedef __attribute__((ext_vector_type(16))) float f32x16;

__device__ inline unsigned short f2h(float f) {
    _Float16 h = (_Float16)f;            // RN conversion
    return __builtin_bit_cast(unsigned short, h);
}

// async global->LDS, 16B per lane; LDS dest = wave-uniform base + lane*16
#define GLDS(g, l) __builtin_amdgcn_global_load_lds(                              \
    (const __attribute__((address_space(1))) unsigned int*)(g),                   \
    (__attribute__((address_space(3))) unsigned int*)(l), 16, 0, 0)

// ---------------------------------------------------------------------------
// NCHW fp32 -> CHUNKED padded NHWC fp16: xh[b][ck=c/16][hp][w][16ci],
// hp in [0,66), rows 0 & 65 zero. Chunked so conv staging reads are 1KB
// contiguous per issue -> zero HBM over-fetch.
// ---------------------------------------------------------------------------
__global__ __launch_bounds__(256) void nchw_to_nhwc_f16(
    const float* __restrict__ x, unsigned short* __restrict__ xh, int C)
{
    const int c0 = blockIdx.x * 64;
    const int hp = blockIdx.y;
    const int b  = blockIdx.z;
    const int nCk = C >> 4;

    if (hp == 0 || hp == 65) {
        for (int idx = threadIdx.x; idx < 1024; idx += 256) {
            int w = idx >> 4, cq = (idx & 15) * 4;
            ushort4 z; z.x = z.y = z.z = z.w = 0;
            *(ushort4*)&xh[((((size_t)b * nCk + (c0 >> 4) + (cq >> 4)) * 66 + hp) * 64 + w) * 16
                           + (cq & 15)] = z;
        }
        return;
    }
    const int h = hp - 1;
    __shared__ float ts[64][65];
    for (int idx = threadIdx.x; idx < 4096; idx += 256) {
        int cl = idx >> 6, w = idx & 63;
        ts[cl][w] = x[(((size_t)b * C + c0 + cl) * 64 + h) * 64 + w];
    }
    __syncthreads();
    for (int idx = threadIdx.x; idx < 1024; idx += 256) {
        int w = idx >> 4, cq = (idx & 15) * 4;
        ushort4 o;
        o.x = f2h(ts[cq + 0][w]); o.y = f2h(ts[cq + 1][w]);
        o.z = f2h(ts[cq + 2][w]); o.w = f2h(ts[cq + 3][w]);
        *(ushort4*)&xh[((((size_t)b * nCk + (c0 >> 4) + (cq >> 4)) * 66 + hp) * 64 + w) * 16
                       + (cq & 15)] = o;
    }
}

// ---------------------------------------------------------------------------
// Pack conv weights [Cout][Cin][3][3] fp32 -> [ck][kk][Cout][16ci] fp16
// ---------------------------------------------------------------------------
__global__ __launch_bounds__(256) void pack_w_kernel(
    const float* __restrict__ w, unsigned short* __restrict__ wT, int Cout, int Cin)
{
    int idx = blockIdx.x * 256 + threadIdx.x;
    int total = Cout * Cin * 9;
    if (idx >= total) return;
    int ci = idx % Cin; int t = idx / Cin; int co = t % Cout; int kk = t / Cout;
    wT[((((size_t)(ci >> 4)) * 9 + kk) * Cout + co) * 16 + (ci & 15)] =
        f2h(w[((size_t)co * Cin + ci) * 9 + kk]);
}

// ---------------------------------------------------------------------------
// Zero the pad rows (0 and 65) of chunked y1h [B][8ck][66][64][16]
// ---------------------------------------------------------------------------
__global__ __launch_bounds__(256) void zero_y1h_pads(unsigned short* __restrict__ y1h)
{
    int idx = blockIdx.x * 256 + threadIdx.x;   // 65536 ushort4 stores
    int b   = idx >> 12;
    int ck  = (idx >> 9) & 7;
    int row = ((idx >> 8) & 1) ? 65 : 0;
    int w   = (idx >> 2) & 63;
    int qtr = idx & 3;
    ushort4 z; z.x = z.y = z.z = z.w = 0;
    *(ushort4*)&y1h[((((size_t)b * 8 + ck) * 66 + row) * 64 + w) * 16 + qtr * 4] = z;
}

// ---------------------------------------------------------------------------
// Implicit-GEMM conv3x3 + BN + SiLU via fp16 MFMA (fp32 accumulate).
// 256 threads = 4 waves; wave w computes TWO output rows (h0+2w, h0+2w+1)
// as 2x2x2 tiles of mfma_f32_32x32x16_f16. The 2-row wave amortizes LDS
// reads: per 16-ci chunk, 72 MFMAs from 18 A-reads + 24 B-reads (weights
// shared across rows; xs rows r..r+3 shared across the rows' kh windows)
// = 0.58 ds_read_b128 per MFMA vs 1.0 for the 1-row structure (LDS pipe
// was the binding resource at ~4.6k cy/chunk/CU vs MFMA 1.15k).
// ci chunked by 16, double-buffered LDS, prefetch before compute. All
// global_load_lds sources 1KB-contiguous. Epilogue: acc -> swizzled LDS
// tile -> dense 1KB-contiguous chunked global writes.
// conv1: outNHWC != nullptr -> chunked padded NHWC y1h.
// conv2: yhi NCHW fp16 (direct stores) + yhiT chunked [b][ck][n][16].
// grid: (Cout/64, 8, B), block 256.
// ---------------------------------------------------------------------------
__global__ __launch_bounds__(256, 2) void conv_mfma_kernel(
    const unsigned short* __restrict__ xh, const unsigned short* __restrict__ wT,
    const float* __restrict__ gamma, const float* __restrict__ beta,
    const float* __restrict__ mean, const float* __restrict__ var,
    unsigned short* __restrict__ outNHWC,
    unsigned short* __restrict__ yhi, unsigned short* __restrict__ yhiT,
    int Cin, int Cout)
{
    const int tid  = threadIdx.x;
    const int wid  = tid >> 6;          // 0..3, wave -> output rows h0+2w,+1
    const int lane = tid & 63;
    const int l31  = lane & 31;
    const int hi   = lane >> 5;
    const int coBase = blockIdx.x * 64;
    const int h0     = blockIdx.y * 8;
    const int b      = blockIdx.z;
    const int nCk    = Cin >> 4;

    // xs[2][10560]: [row 0..9][col 0..65][16ci]; ws[2][9216]: [kk][64co][16ci]
    // epilogue reuses smem[0..32767] as os[8 row][64 w][64 co] (swizzled)
    __shared__ __align__(16) unsigned short smem[39552];   // 79104 B
    __shared__ float bnsc[64], bnsh[64];

    if (tid < 64) {
        int co = coBase + tid;
        float sc = gamma[co] * rsqrtf(var[co] + 1e-5f);
        bnsc[tid] = sc;
        bnsh[tid] = beta[co] - mean[co] * sc;
    }
    if (tid < 160) {   // zero halo cols 0 and 65, rows 0..9, both buffers
        int cell = tid >> 2;                // 0..39
        int part = tid & 3;
        int buf  = cell & 1;
        int col  = ((cell >> 1) & 1) ? 65 : 0;
        int r    = cell >> 2;               // 0..9
        ushort4 z; z.x = z.y = z.z = z.w = 0;
        *(ushort4*)&smem[buf * 10560 + (r * 66 + col) * 16 + part * 4] = z;
    }

    // stage one 16-ci chunk: 18 ws issues + 20 xs issues, all 1KB contiguous
    auto stage = [&](int sel, int ck) {
        unsigned short* wsd = smem + 21120 + sel * 9216;
        unsigned short* xsd = smem + sel * 10560;
        for (int it = wid; it < 38; it += 4) {
            if (it < 18) {
                int kk = it >> 1, h = it & 1;
                const unsigned short* g =
                    wT + (((size_t)ck * 9 + kk) * Cout + coBase + h * 32) * 16 + lane * 8;
                GLDS(g, wsd + (kk * 64 + h * 32) * 16);
            } else {
                int j = it - 18;                 // 0..19
                int r = j >> 1, hf = j & 1;
                const unsigned short* g =
                    xh + ((((size_t)b * nCk + ck) * 66 + h0 + r) * 64 + hf * 32) * 16 + lane * 8;
                GLDS(g, xsd + (r * 66 + 1 + hf * 32) * 16);
            }
        }
    };

    stage(0, 0);
    __syncthreads();

    f32x16 acc[2][2][2] = {};    // [row2][mi(co)][ni(w)]
    const int lr = wid * 2;      // wave's first padded row in block window

    int sel = 0;
    for (int ck = 0; ck < nCk; ck++) {
        if (ck + 1 < nCk) stage(sel ^ 1, ck + 1);   // prefetch next chunk

        const unsigned short* wsb = smem + 21120 + sel * 9216;
        const unsigned short* xsb = smem + sel * 10560;

        half8 Aprev[2][3];
#pragma unroll
        for (int rr = 0; rr < 4; rr++) {
            // B frags for xs row lr+rr (shared by both output rows)
            half8 bfr[2][3];
#pragma unroll
            for (int ni = 0; ni < 2; ni++)
#pragma unroll
                for (int kw = 0; kw < 3; kw++)
                    bfr[ni][kw] = *(const half8*)
                        &xsb[((lr + rr) * 66 + ni * 32 + l31 + kw) * 16 + hi * 8];

            half8 Acur[2][3];
            if (rr < 3) {   // A frags for kh = rr (kk = rr*3+kw)
#pragma unroll
                for (int mi = 0; mi < 2; mi++)
#pragma unroll
                    for (int kw = 0; kw < 3; kw++)
                        Acur[mi][kw] = *(const half8*)
                            &wsb[((rr * 3 + kw) * 64 + mi * 32 + l31) * 16 + hi * 8];
            }
            if (rr < 3) {   // out row0 uses kh = rr
#pragma unroll
                for (int kw = 0; kw < 3; kw++)
#pragma unroll
                    for (int mi = 0; mi < 2; mi++)
#pragma unroll
                        for (int ni = 0; ni < 2; ni++)
                            acc[0][mi][ni] = __builtin_amdgcn_mfma_f32_32x32x16_f16(
                                Acur[mi][kw], bfr[ni][kw], acc[0][mi][ni], 0, 0, 0);
            }
            if (rr >= 1) {  // out row1 uses kh = rr-1 (A from previous rr)
#pragma unroll
                for (int kw = 0; kw < 3; kw++)
#pragma unroll
                    for (int mi = 0; mi < 2; mi++)
#pragma unroll
                        for (int ni = 0; ni < 2; ni++)
                            acc[1][mi][ni] = __builtin_amdgcn_mfma_f32_32x32x16_f16(
                                Aprev[mi][kw], bfr[ni][kw], acc[1][mi][ni], 0, 0, 0);
            }
#pragma unroll
            for (int mi = 0; mi < 2; mi++)
#pragma unroll
                for (int kw = 0; kw < 3; kw++)
                    Aprev[mi][kw] = Acur[mi][kw];
        }
        __syncthreads();   // next buffer staged + this buffer free to overwrite
        sel ^= 1;
    }

    // --------------------------------------------------------------
    // Epilogue. D layout (32x32): col=lane&31 -> w,
    // row = (reg&3) + 8*(reg>>2) + 4*hi -> co.
    // Stage BN+SiLU fp16 results into os[row][w][co] with XOR swizzle
    // ((w+row)&7)<<3 on the co-offset, then dense 1KB chunked writes.
    // --------------------------------------------------------------
    const bool isConv1 = (outNHWC != nullptr);

#pragma unroll
    for (int r2 = 0; r2 < 2; r2++) {
        const int lrow = lr + r2;        // 0..7
        const int orow = h0 + lrow;
#pragma unroll
        for (int mi = 0; mi < 2; mi++)
#pragma unroll
            for (int ni = 0; ni < 2; ni++) {
                f32x16 a = acc[r2][mi][ni];
                int w = ni * 32 + l31;
                int swz = ((l31 + lrow) & 7) << 3;
#pragma unroll
                for (int rq = 0; rq < 4; rq++) {
                    int c0 = mi * 32 + rq * 8 + hi * 4;   // local co base
                    ushort4 o; unsigned short* op = (unsigned short*)&o;
#pragma unroll
                    for (int r = 0; r < 4; r++) {
                        float t = a[rq * 4 + r] * bnsc[c0 + r] + bnsh[c0 + r];
                        float s = t / (1.f + __expf(-t));
                        op[r] = f2h(s);
                        if (!isConv1)
                            yhi[(((size_t)b * Cout + coBase + c0 + r) * 64 + orow) * 64 + w]
                                = op[r];
                    }
                    *(ushort4*)&smem[lrow * 4096 + w * 64 + (c0 ^ swz)] = o;
                }
            }
    }
    __syncthreads();

    // dense write-out: 4096 16B units = [ck(4)][row(8)][w(64)][s(2)];
    // unit g = j*256 + tid -> each instruction writes 1KB contiguous.
    const int ckB = blockIdx.x * 4;   // output chunk base
    const int nCkOut = Cout >> 4;
#pragma unroll
    for (int j = 0; j < 16; j++) {
        int g   = j * 256 + tid;
        int s   = g & 1;
        int w   = (g >> 1) & 63;
        int row = (g >> 7) & 7;
        int ck  = g >> 10;
        uint4 v = *(const uint4*)&smem[row * 4096 + w * 64 +
                     (((ck * 2 + s) * 8) ^ (((w + row) & 7) << 3))];
        if (isConv1) {
            *(uint4*)&outNHWC[((((size_t)b * nCkOut + ckB + ck) * 66 + h0 + row + 1) * 64 + w) * 16
                              + s * 8] = v;
        } else {
            *(uint4*)&yhiT[(((size_t)b * nCkOut + ckB + ck) * 4096 + (size_t)(h0 + row) * 64 + w) * 16
                           + s * 8] = v;
        }
    }
}

// ---------------------------------------------------------------------------
// scores = (y . y^T)/16, fp16 MFMA, SYMMETRIC: only upper-triangle 64x64 tile
// pairs are computed (10 of 16); each writes its tile and the transpose.
// y_hi: [b][c=256][n=4096] fp16. Block: 4 waves of 32x32. K-chunks of 128,
// XOR-swizzled LDS (conflict-free ds_read_b128).
// grid: (10, 1, 16)
// ---------------------------------------------------------------------------
__global__ __launch_bounds__(256) void scores_mfma_kernel(
    const unsigned short* __restrict__ yhi, float* __restrict__ scores)
{
    static const int TI[10] = {0,0,0,0,1,1,1,2,2,3};
    static const int TJ[10] = {0,1,2,3,1,2,3,2,3,3};
    const int b  = blockIdx.z;
    const int ti = TI[blockIdx.x], tj = TJ[blockIdx.x];
    const int cB = ti * 64;
    const int dB = tj * 64;
    const int tid  = threadIdx.x;
    const int wid  = tid >> 6;
    const int lane = tid & 63;
    const int ln   = lane & 15;
    const int q    = lane >> 4;
    const int wm   = wid >> 1, wn = wid & 1;

    __shared__ unsigned short As[64 * 128];  // 16 KB, rows cB..cB+63, swizzled
    __shared__ unsigned short Bs[64 * 128];  // 16 KB, rows dB..dB+63, swizzled

    const int rl = lane >> 4;
    const int gl = lane & 15;

    f32x4 acc[2][2] = {};

    for (int ck = 0; ck < 32; ck++) {
        const int n0 = ck * 128;
        for (int it = wid; it < 32; it += 4) {
            const int tile = it >> 4;
            const int j = it & 15;
            const int r = j * 4 + rl;
            const int gq = gl ^ (r & 7);
            const int rowAbs = (tile ? dB : cB) + r;
            const unsigned short* g =
                yhi + ((size_t)b * 256 + rowAbs) * 4096 + n0 + gq * 8;
            GLDS(g, (tile ? Bs : As) + j * 512);
        }
        __syncthreads();

#pragma unroll
        for (int kwin = 0; kwin < 4; kwin++) {
            half8 ah[2], bh[2];
#pragma unroll
            for (int mi = 0; mi < 2; mi++) {
                int row = wm * 32 + mi * 16 + ln;
                ah[mi] = *(const half8*)&As[row * 128 + ((kwin * 4 + q) ^ (ln & 7)) * 8];
            }
#pragma unroll
            for (int ni = 0; ni < 2; ni++) {
                int row = wn * 32 + ni * 16 + ln;
                bh[ni] = *(const half8*)&Bs[row * 128 + ((kwin * 4 + q) ^ (ln & 7)) * 8];
            }
#pragma unroll
            for (int mi = 0; mi < 2; mi++)
#pragma unroll
                for (int ni = 0; ni < 2; ni++)
                    acc[mi][ni] = __builtin_amdgcn_mfma_f32_16x16x32_f16(
                        ah[mi], bh[ni], acc[mi][ni], 0, 0, 0);
        }
        __syncthreads();
    }

#pragma unroll
    for (int mi = 0; mi < 2; mi++)
#pragma unroll
        for (int ni = 0; ni < 2; ni++) {
            f32x4 a = acc[mi][ni];
            float vals[4];
            vals[0] = a.x * INV_T; vals[1] = a.y * INV_T;
            vals[2] = a.z * INV_T; vals[3] = a.w * INV_T;
            int c0 = cB + wm * 32 + mi * 16 + q * 4;
            int d  = dB + wn * 32 + ni * 16 + ln;
#pragma unroll
            for (int r = 0; r < 4; r++)
                scores[((size_t)b * C1 + c0 + r) * C1 + d] = vals[r];
            if (ti != tj) {   // mirror tile
                float4 tv = {vals[0], vals[1], vals[2], vals[3]};
                *(float4*)&scores[((size_t)b * C1 + d) * C1 + c0] = tv;
            }
        }
}

// ---------------------------------------------------------------------------
// Row softmax over 256 entries; reads fp32 scores, writes fp16 attn.
// ---------------------------------------------------------------------------
__global__ __launch_bounds__(64) void softmax_kernel(
    const float* __restrict__ scores, unsigned short* __restrict__ attn16)
{
    const int row = blockIdx.x;
    const float* p = scores + (size_t)row * C1;
    const int lane = threadIdx.x;

    float4 v = ((const float4*)p)[lane];
    float m = fmaxf(fmaxf(v.x, v.y), fmaxf(v.z, v.w));
#pragma unroll
    for (int off = 32; off >= 1; off >>= 1)
        m = fmaxf(m, __shfl_xor(m, off, 64));

    float4 e;
    e.x = expf(v.x - m); e.y = expf(v.y - m);
    e.z = expf(v.z - m); e.w = expf(v.w - m);
    float s = e.x + e.y + e.z + e.w;
#pragma unroll
    for (int off = 32; off >= 1; off >>= 1)
        s += __shfl_xor(s, off, 64);
    float inv = 1.f / s;
    ushort4 o;
    o.x = f2h(e.x * inv); o.y = f2h(e.y * inv);
    o.z = f2h(e.z * inv); o.w = f2h(e.w * inv);
    *(ushort4*)&attn16[(size_t)row * C1 + lane * 4] = o;
}

// ---------------------------------------------------------------------------
// out[b][c][n] = x[b][c][n] + sum_d attn[c][d] * y[d][n]  via fp16 MFMA.
// A = attn16 [b][c][d] (k=d contiguous); B = yhiT CHUNKED [b][d/16][n][16d].
// Block tile 64c x 128n, 4 waves of 32x64. K-chunks of 64 (4 chunks).
// Bs staging reads 1KB-contiguous spans of the chunked layout.
// grid: (32, 4, 16)
// ---------------------------------------------------------------------------
__global__ __launch_bounds__(256) void out_mfma_kernel(
    const unsigned short* __restrict__ attn16, const unsigned short* __restrict__ yhiT,
    const float* __restrict__ x, float* __restrict__ out)
{
    const int b  = blockIdx.z;
    const int cB = blockIdx.y * 64;
    const int nB = blockIdx.x * 128;
    const int tid  = threadIdx.x;
    const int wid  = tid >> 6;
    const int lane = tid & 63;
    const int ln   = lane & 15;
    const int q    = lane >> 4;
    const int wm   = wid >> 1, wn = wid & 1;

    __shared__ unsigned short As[64 * 64];    //  8 KB, XOR-swizzled
    __shared__ unsigned short Bs[4 * 128 * 16];   // 16 KB: [u(4 d-sub)][128 n][16d]

    const int r8 = lane >> 3;
    const int gq = (lane & 7) ^ r8;

    f32x4 acc[2][4] = {};

    for (int ck = 0; ck < 4; ck++) {
        const int d0 = ck * 64;
        for (int it = wid; it < 24; it += 4) {
            if (it < 8) {
                const unsigned short* g =
                    attn16 + ((size_t)b * 256 + cB + it * 8 + r8) * 256 + d0 + gq * 8;
                GLDS(g, As + it * 512);
            } else {
                int j = it - 8;            // 0..15
                int u = j >> 2, part = j & 3;
                const unsigned short* g =
                    yhiT + (((size_t)b * 16 + ck * 4 + u) * 4096 + nB + part * 32) * 16 + lane * 8;
                GLDS(g, Bs + (u * 128 + part * 32) * 16);
            }
        }
        __syncthreads();

#pragma unroll
        for (int kwin = 0; kwin < 2; kwin++) {
            const int cc = (((kwin * 4 + q) ^ (ln & 7))) * 8;
            const int gK = kwin * 4 + q;
            half8 af[2], bfr[4];
#pragma unroll
            for (int mi = 0; mi < 2; mi++)
                af[mi] = *(const half8*)&As[(wm * 32 + mi * 16 + ln) * 64 + cc];
#pragma unroll
            for (int ni = 0; ni < 4; ni++) {
                int row = wn * 64 + ni * 16 + ln;
                bfr[ni] = *(const half8*)&Bs[(gK >> 1) * 2048 + row * 16 + (gK & 1) * 8];
            }
#pragma unroll
            for (int mi = 0; mi < 2; mi++)
#pragma unroll
                for (int ni = 0; ni < 4; ni++)
                    acc[mi][ni] = __builtin_amdgcn_mfma_f32_16x16x32_f16(
                        af[mi], bfr[ni], acc[mi][ni], 0, 0, 0);
        }
        __syncthreads();
    }

#pragma unroll
    for (int mi = 0; mi < 2; mi++)
#pragma unroll
        for (int ni = 0; ni < 4; ni++) {
            f32x4 a = acc[mi][ni];
            float vals[4] = {a.x, a.y, a.z, a.w};
#pragma unroll
            for (int r = 0; r < 4; r++) {
                int c = cB + wm * 32 + mi * 16 + q * 4 + r;
                int n = nB + wn * 64 + ni * 16 + ln;
                size_t o = ((size_t)b * C1 + c) * NN + n;
                out[o] = x[o] + vals[r];
            }
        }
}

// ---------------------------------------------------------------------------
extern "C" void kernel_launch(void* const* d_in, const int* in_sizes, int n_in,
                              void* d_out, int out_size, void* d_ws, size_t ws_size,
                              hipStream_t stream)
{
    const float* x  = (const float*)d_in[0];
    const float* w1 = (const float*)d_in[1];
    const float* g1 = (const float*)d_in[2];
    const float* b1 = (const float*)d_in[3];
    const float* m1 = (const float*)d_in[4];
    const float* v1 = (const float*)d_in[5];
    const float* w2 = (const float*)d_in[6];
    const float* g2 = (const float*)d_in[7];
    const float* b2 = (const float*)d_in[8];
    const float* m2 = (const float*)d_in[9];
    const float* v2 = (const float*)d_in[10];
    float* out = (float*)d_out;

    // workspace (86.6 MB total):
    //  xh [17,301,504 us] -- dead after conv1, REUSED as y_hi [16,777,216 us]
    //  y1h [8,650,752 us] -- dead after conv2, REUSED as sc (fp32) + attn16
    unsigned short* xh   = (unsigned short*)d_ws;
    unsigned short* y1h  = xh  + (size_t)17301504;
    unsigned short* wt1  = y1h + (size_t)8650752;
    unsigned short* wt2  = wt1 + (size_t)294912;
    unsigned short* yhiT = wt2 + (size_t)294912;
    unsigned short* yhi  = xh;                         // alias (xh dead)
    float*          sc   = (float*)y1h;                // alias (y1h dead)
    unsigned short* attn16 = (unsigned short*)(sc + 1048576);

    // pre-pass
    nchw_to_nhwc_f16<<<dim3(C1 / 64, 66, BB), 256, 0, stream>>>(x, xh, C1);
    pack_w_kernel<<<(9 * CHD * C1 + 255) / 256, 256, 0, stream>>>(w1, wt1, CHD, C1);
    pack_w_kernel<<<(9 * C1 * CHD + 255) / 256, 256, 0, stream>>>(w2, wt2, C1, CHD);
    zero_y1h_pads<<<256, 256, 0, stream>>>(y1h);

    // conv1: 256 -> 128, chunked fp16 NHWC out (padded rows)
    conv_mfma_kernel<<<dim3(CHD / 64, 8, BB), 256, 0, stream>>>(
        xh, wt1, g1, b1, m1, v1, y1h, nullptr, nullptr, C1, CHD);
    // conv2: 128 -> 256, y_hi NCHW + yhiT chunked NHWC (overwrites xh region)
    conv_mfma_kernel<<<dim3(C1 / 64, 8, BB), 256, 0, stream>>>(
        y1h, wt2, g2, b2, m2, v2, nullptr, yhi, yhiT, CHD, C1);

    // attention: symmetric fp16 MFMA scores -> softmax -> fp16 MFMA PV + residual
    scores_mfma_kernel<<<dim3(10, 1, BB), 256, 0, stream>>>(yhi, sc);
    softmax_kernel<<<dim3(BB * C1), 64, 0, stream>>>(sc, attn16);
    out_mfma_kernel<<<dim3(NN / 128, 4, BB), 256, 0, stream>>>(attn16, yhiT, x, out);
}

// Round 4
// 299.829 us; speedup vs baseline: 1.1112x; 1.1112x over previous
//
#include <hip/hip_runtime.h>
#include <math.h>

// Problem constants
#define BB 16
#define C1 256     // in/out channels of the block
#define CHD 128    // hidden channels
#define NN 4096    // H*W
#define INV_T (1.0f/16.0f)   // TEMPERATURE = sqrt(256) = 16

typedef _Float16 half8 __attribute__((ext_vector_type(8)));
typedef __attribute__((ext_vector_type(4))) float f32x4;
typedef __attribute__((ext_vector_type(16))) float f32x16;

__device__ inline unsigned short f2h(float f) {
    _Float16 h = (_Float16)f;            // RN conversion
    return __builtin_bit_cast(unsigned short, h);
}

// async global->LDS, 16B per lane; LDS dest = wave-uniform base + lane*16
#define GLDS(g, l) __builtin_amdgcn_global_load_lds(                              \
    (const __attribute__((address_space(1))) unsigned int*)(g),                   \
    (__attribute__((address_space(3))) unsigned int*)(l), 16, 0, 0)

// XCD-chunked bijective blockIdx swizzle (T1). HW dispatch order is
// x-fastest linear, round-robin over 8 XCDs. Remap so each XCD gets a
// CONTIGUOUS logical range (requires nwg % 8 == 0 -- all our grids).
// Unflattened x-fastest, so logical-consecutive = co/tile blocks that
// share operand panels -> L2 reuse within an XCD.
__device__ inline void xcd_remap(int& bx, int& by, int& bz) {
    int gx = gridDim.x, gy = gridDim.y;
    int lin = blockIdx.x + gx * (blockIdx.y + gy * blockIdx.z);
    int cpx = (gx * gy * (int)gridDim.z) >> 3;
    lin = (lin & 7) * cpx + (lin >> 3);
    bx = lin % gx; int t = lin / gx; by = t % gy; bz = t / gy;
}

// ---------------------------------------------------------------------------
// NCHW fp32 -> CHUNKED padded NHWC fp16: xh[b][ck=c/16][hp][w][16ci],
// hp in [0,66), rows 0 & 65 zero.
// ---------------------------------------------------------------------------
__global__ __launch_bounds__(256) void nchw_to_nhwc_f16(
    const float* __restrict__ x, unsigned short* __restrict__ xh, int C)
{
    const int c0 = blockIdx.x * 64;
    const int hp = blockIdx.y;
    const int b  = blockIdx.z;
    const int nCk = C >> 4;

    if (hp == 0 || hp == 65) {
        for (int idx = threadIdx.x; idx < 1024; idx += 256) {
            int w = idx >> 4, cq = (idx & 15) * 4;
            ushort4 z; z.x = z.y = z.z = z.w = 0;
            *(ushort4*)&xh[((((size_t)b * nCk + (c0 >> 4) + (cq >> 4)) * 66 + hp) * 64 + w) * 16
                           + (cq & 15)] = z;
        }
        return;
    }
    const int h = hp - 1;
    __shared__ float ts[64][65];
    for (int idx = threadIdx.x; idx < 4096; idx += 256) {
        int cl = idx >> 6, w = idx & 63;
        ts[cl][w] = x[(((size_t)b * C + c0 + cl) * 64 + h) * 64 + w];
    }
    __syncthreads();
    for (int idx = threadIdx.x; idx < 1024; idx += 256) {
        int w = idx >> 4, cq = (idx & 15) * 4;
        ushort4 o;
        o.x = f2h(ts[cq + 0][w]); o.y = f2h(ts[cq + 1][w]);
        o.z = f2h(ts[cq + 2][w]); o.w = f2h(ts[cq + 3][w]);
        *(ushort4*)&xh[((((size_t)b * nCk + (c0 >> 4) + (cq >> 4)) * 66 + hp) * 64 + w) * 16
                       + (cq & 15)] = o;
    }
}

// ---------------------------------------------------------------------------
// Pack conv weights [Cout][Cin][3][3] fp32 -> [ck][kk][Cout][16ci] fp16
// ---------------------------------------------------------------------------
__global__ __launch_bounds__(256) void pack_w_kernel(
    const float* __restrict__ w, unsigned short* __restrict__ wT, int Cout, int Cin)
{
    int idx = blockIdx.x * 256 + threadIdx.x;
    int total = Cout * Cin * 9;
    if (idx >= total) return;
    int ci = idx % Cin; int t = idx / Cin; int co = t % Cout; int kk = t / Cout;
    wT[((((size_t)(ci >> 4)) * 9 + kk) * Cout + co) * 16 + (ci & 15)] =
        f2h(w[((size_t)co * Cin + ci) * 9 + kk]);
}

// ---------------------------------------------------------------------------
// Zero the pad rows (0 and 65) of chunked y1h [B][8ck][66][64][16]
// ---------------------------------------------------------------------------
__global__ __launch_bounds__(256) void zero_y1h_pads(unsigned short* __restrict__ y1h)
{
    int idx = blockIdx.x * 256 + threadIdx.x;   // 65536 ushort4 stores
    int b   = idx >> 12;
    int ck  = (idx >> 9) & 7;
    int row = ((idx >> 8) & 1) ? 65 : 0;
    int w   = (idx >> 2) & 63;
    int qtr = idx & 3;
    ushort4 z; z.x = z.y = z.z = z.w = 0;
    *(ushort4*)&y1h[((((size_t)b * 8 + ck) * 66 + row) * 64 + w) * 16 + qtr * 4] = z;
}

// ---------------------------------------------------------------------------
// Implicit-GEMM conv3x3 + BN + SiLU via fp16 MFMA (fp32 accumulate).
// R2 structure (best measured): 512 threads = 8 waves; wave w computes
// output row h0+w as a 2x2 tile of mfma_f32_32x32x16_f16. ci chunked by
// 16, double-buffered LDS, prefetch before compute, one barrier/chunk.
// All global_load_lds sources 1KB-contiguous (chunked layouts).
// NEW: XCD-chunked blockIdx swizzle (same-band co-blocks share y1h/xh
// L2 lines within an XCD) + s_setprio around the MFMA cluster.
// conv1: outNHWC != nullptr -> chunked padded NHWC y1h.
// conv2: yhi NCHW fp16 (direct stores) + yhiT chunked [b][ck][n][16].
// grid: (Cout/64, 8, B), block 512.
// ---------------------------------------------------------------------------
__global__ __launch_bounds__(512, 4) void conv_mfma_kernel(
    const unsigned short* __restrict__ xh, const unsigned short* __restrict__ wT,
    const float* __restrict__ gamma, const float* __restrict__ beta,
    const float* __restrict__ mean, const float* __restrict__ var,
    unsigned short* __restrict__ outNHWC,
    unsigned short* __restrict__ yhi, unsigned short* __restrict__ yhiT,
    int Cin, int Cout)
{
    int bx, by, bz;
    xcd_remap(bx, by, bz);
    const int tid  = threadIdx.x;
    const int wid  = tid >> 6;          // 0..7, wave -> output row h0+wid
    const int lane = tid & 63;
    const int l31  = lane & 31;
    const int hi   = lane >> 5;
    const int coBase = bx * 64;
    const int h0     = by * 8;
    const int b      = bz;
    const int nCk    = Cin >> 4;

    // xs[2][10560]: [row 0..9][col 0..65][16ci]; ws[2][9216]: [kk][64co][16ci]
    // epilogue reuses smem[0..32767] as os[8 row][64 w][64 co] (swizzled)
    __shared__ __align__(16) unsigned short smem[39552];   // 79104 B
    __shared__ float bnsc[64], bnsh[64];

    if (tid < 64) {
        int co = coBase + tid;
        float sc = gamma[co] * rsqrtf(var[co] + 1e-5f);
        bnsc[tid] = sc;
        bnsh[tid] = beta[co] - mean[co] * sc;
    }
    if (tid < 160) {   // zero halo cols 0 and 65, rows 0..9, both buffers
        int cell = tid >> 2;                // 0..39
        int part = tid & 3;
        int buf  = cell & 1;
        int col  = ((cell >> 1) & 1) ? 65 : 0;
        int r    = cell >> 2;               // 0..9
        ushort4 z; z.x = z.y = z.z = z.w = 0;
        *(ushort4*)&smem[buf * 10560 + (r * 66 + col) * 16 + part * 4] = z;
    }

    // stage one 16-ci chunk: 18 ws issues + 20 xs issues, all 1KB contiguous
    auto stage = [&](int sel, int ck) {
        unsigned short* wsd = smem + 21120 + sel * 9216;
        unsigned short* xsd = smem + sel * 10560;
        for (int it = wid; it < 38; it += 8) {
            if (it < 18) {
                int kk = it >> 1, h = it & 1;
                const unsigned short* g =
                    wT + (((size_t)ck * 9 + kk) * Cout + coBase + h * 32) * 16 + lane * 8;
                GLDS(g, wsd + (kk * 64 + h * 32) * 16);
            } else {
                int j = it - 18;                 // 0..19
                int r = j >> 1, hf = j & 1;
                const unsigned short* g =
                    xh + ((((size_t)b * nCk + ck) * 66 + h0 + r) * 64 + hf * 32) * 16 + lane * 8;
                GLDS(g, xsd + (r * 66 + 1 + hf * 32) * 16);
            }
        }
    };

    stage(0, 0);
    __syncthreads();

    f32x16 acc[2][2] = {};

    int sel = 0;
    for (int ck = 0; ck < nCk; ck++) {
        if (ck + 1 < nCk) stage(sel ^ 1, ck + 1);   // prefetch next chunk

        const unsigned short* wsb = smem + 21120 + sel * 9216;
        const unsigned short* xsb = smem + sel * 10560;
        __builtin_amdgcn_s_setprio(1);
#pragma unroll
        for (int kk = 0; kk < 9; kk++) {
            const int kh = kk / 3, kw = kk % 3;
            half8 a0 = *(const half8*)&wsb[(kk * 64 +      l31) * 16 + hi * 8];
            half8 a1 = *(const half8*)&wsb[(kk * 64 + 32 + l31) * 16 + hi * 8];
            const unsigned short* xr = &xsb[((wid + kh) * 66 + l31 + kw) * 16 + hi * 8];
            half8 b0 = *(const half8*)xr;
            half8 b1 = *(const half8*)&xr[32 * 16];
            acc[0][0] = __builtin_amdgcn_mfma_f32_32x32x16_f16(a0, b0, acc[0][0], 0, 0, 0);
            acc[0][1] = __builtin_amdgcn_mfma_f32_32x32x16_f16(a0, b1, acc[0][1], 0, 0, 0);
            acc[1][0] = __builtin_amdgcn_mfma_f32_32x32x16_f16(a1, b0, acc[1][0], 0, 0, 0);
            acc[1][1] = __builtin_amdgcn_mfma_f32_32x32x16_f16(a1, b1, acc[1][1], 0, 0, 0);
        }
        __builtin_amdgcn_s_setprio(0);
        __syncthreads();   // next buffer staged + this buffer free to overwrite
        sel ^= 1;
    }

    // --------------------------------------------------------------
    // Epilogue. D layout (32x32): col=lane&31 -> w,
    // row = (reg&3) + 8*(reg>>2) + 4*hi -> co.
    // Stage BN+SiLU fp16 results into os[row][w][co] with XOR swizzle
    // ((w+row)&7)<<3 on the co-offset, then dense 1KB chunked writes.
    // --------------------------------------------------------------
    const int orow = h0 + wid;
    const bool isConv1 = (outNHWC != nullptr);

    __syncthreads();   // all K-loop LDS reads done before overwrite

#pragma unroll
    for (int mi = 0; mi < 2; mi++)
#pragma unroll
        for (int ni = 0; ni < 2; ni++) {
            f32x16 a = acc[mi][ni];
            int w = ni * 32 + l31;
            int swz = ((l31 + wid) & 7) << 3;
#pragma unroll
            for (int rq = 0; rq < 4; rq++) {
                int c0 = mi * 32 + rq * 8 + hi * 4;   // local co base
                ushort4 o; unsigned short* op = (unsigned short*)&o;
#pragma unroll
                for (int r = 0; r < 4; r++) {
                    float t = a[rq * 4 + r] * bnsc[c0 + r] + bnsh[c0 + r];
                    float s = t / (1.f + __expf(-t));
                    op[r] = f2h(s);
                    if (!isConv1)
                        yhi[(((size_t)b * Cout + coBase + c0 + r) * 64 + orow) * 64 + w] = op[r];
                }
                *(ushort4*)&smem[wid * 4096 + w * 64 + (c0 ^ swz)] = o;
            }
        }
    __syncthreads();

    // dense write-out: 4096 16B units = [ck(4)][row(8)][w(64)][s(2)];
    // unit g = j*512 + tid -> each instruction writes 1KB contiguous.
    const int ckB = bx * 4;   // output chunk base
    const int nCkOut = Cout >> 4;
#pragma unroll
    for (int j = 0; j < 8; j++) {
        int g   = j * 512 + tid;
        int s   = g & 1;
        int w   = (g >> 1) & 63;
        int row = (g >> 7) & 7;
        int ck  = g >> 10;
        uint4 v = *(const uint4*)&smem[row * 4096 + w * 64 +
                     (((ck * 2 + s) * 8) ^ (((w + row) & 7) << 3))];
        if (isConv1) {
            *(uint4*)&outNHWC[((((size_t)b * nCkOut + ckB + ck) * 66 + h0 + row + 1) * 64 + w) * 16
                              + s * 8] = v;
        } else {
            *(uint4*)&yhiT[(((size_t)b * nCkOut + ckB + ck) * 4096 + (size_t)(h0 + row) * 64 + w) * 16
                           + s * 8] = v;
        }
    }
}

// ---------------------------------------------------------------------------
// scores = (y . y^T)/16, fp16 MFMA, SYMMETRIC: only upper-triangle 64x64 tile
// pairs computed (10 of 16); each writes its tile and the transpose.
// SPLIT-K x2: blockIdx.y = kh selects n-half (16 of 32 chunks); partial
// fp32 scores go to scores + kh*1048576; softmax sums the two halves.
// (160 -> 320 blocks: 2.5 -> 5 waves/CU, halves the serial chunk chain.)
// grid: (10, 2, 16)
// ---------------------------------------------------------------------------
__global__ __launch_bounds__(256) void scores_mfma_kernel(
    const unsigned short* __restrict__ yhi, float* __restrict__ scores)
{
    static const int TI[10] = {0,0,0,0,1,1,1,2,2,3};
    static const int TJ[10] = {0,1,2,3,1,2,3,2,3,3};
    int bx, by, bz;
    xcd_remap(bx, by, bz);
    const int b  = bz;
    const int kh = by;
    const int ti = TI[bx], tj = TJ[bx];
    const int cB = ti * 64;
    const int dB = tj * 64;
    const int tid  = threadIdx.x;
    const int wid  = tid >> 6;
    const int lane = tid & 63;
    const int ln   = lane & 15;
    const int q    = lane >> 4;
    const int wm   = wid >> 1, wn = wid & 1;

    float* scp = scores + (size_t)kh * 1048576;   // partial buffer for this half

    __shared__ unsigned short As[64 * 128];  // 16 KB, rows cB..cB+63, swizzled
    __shared__ unsigned short Bs[64 * 128];  // 16 KB, rows dB..dB+63, swizzled

    const int rl = lane >> 4;
    const int gl = lane & 15;

    f32x4 acc[2][2] = {};

    for (int ck = kh * 16; ck < kh * 16 + 16; ck++) {
        const int n0 = ck * 128;
        for (int it = wid; it < 32; it += 4) {
            const int tile = it >> 4;
            const int j = it & 15;
            const int r = j * 4 + rl;
            const int gq = gl ^ (r & 7);
            const int rowAbs = (tile ? dB : cB) + r;
            const unsigned short* g =
                yhi + ((size_t)b * 256 + rowAbs) * 4096 + n0 + gq * 8;
            GLDS(g, (tile ? Bs : As) + j * 512);
        }
        __syncthreads();

#pragma unroll
        for (int kwin = 0; kwin < 4; kwin++) {
            half8 ah[2], bh[2];
#pragma unroll
            for (int mi = 0; mi < 2; mi++) {
                int row = wm * 32 + mi * 16 + ln;
                ah[mi] = *(const half8*)&As[row * 128 + ((kwin * 4 + q) ^ (ln & 7)) * 8];
            }
#pragma unroll
            for (int ni = 0; ni < 2; ni++) {
                int row = wn * 32 + ni * 16 + ln;
                bh[ni] = *(const half8*)&Bs[row * 128 + ((kwin * 4 + q) ^ (ln & 7)) * 8];
            }
#pragma unroll
            for (int mi = 0; mi < 2; mi++)
#pragma unroll
                for (int ni = 0; ni < 2; ni++)
                    acc[mi][ni] = __builtin_amdgcn_mfma_f32_16x16x32_f16(
                        ah[mi], bh[ni], acc[mi][ni], 0, 0, 0);
        }
        __syncthreads();
    }

#pragma unroll
    for (int mi = 0; mi < 2; mi++)
#pragma unroll
        for (int ni = 0; ni < 2; ni++) {
            f32x4 a = acc[mi][ni];
            float vals[4];
            vals[0] = a.x * INV_T; vals[1] = a.y * INV_T;
            vals[2] = a.z * INV_T; vals[3] = a.w * INV_T;
            int c0 = cB + wm * 32 + mi * 16 + q * 4;
            int d  = dB + wn * 32 + ni * 16 + ln;
#pragma unroll
            for (int r = 0; r < 4; r++)
                scp[((size_t)b * C1 + c0 + r) * C1 + d] = vals[r];
            if (ti != tj) {   // mirror tile
                float4 tv = {vals[0], vals[1], vals[2], vals[3]};
                *(float4*)&scp[((size_t)b * C1 + d) * C1 + c0] = tv;
            }
        }
}

// ---------------------------------------------------------------------------
// Row softmax over 256 entries; sums the two split-K partial fp32 buffers,
// writes fp16 attn.
// ---------------------------------------------------------------------------
__global__ __launch_bounds__(64) void softmax_kernel(
    const float* __restrict__ scores, unsigned short* __restrict__ attn16)
{
    const int row = blockIdx.x;
    const float* p = scores + (size_t)row * C1;
    const int lane = threadIdx.x;

    float4 v0 = ((const float4*)p)[lane];
    float4 v1 = ((const float4*)(p + 1048576))[lane];
    float4 v;
    v.x = v0.x + v1.x; v.y = v0.y + v1.y;
    v.z = v0.z + v1.z; v.w = v0.w + v1.w;
    float m = fmaxf(fmaxf(v.x, v.y), fmaxf(v.z, v.w));
#pragma unroll
    for (int off = 32; off >= 1; off >>= 1)
        m = fmaxf(m, __shfl_xor(m, off, 64));

    float4 e;
    e.x = expf(v.x - m); e.y = expf(v.y - m);
    e.z = expf(v.z - m); e.w = expf(v.w - m);
    float s = e.x + e.y + e.z + e.w;
#pragma unroll
    for (int off = 32; off >= 1; off >>= 1)
        s += __shfl_xor(s, off, 64);
    float inv = 1.f / s;
    ushort4 o;
    o.x = f2h(e.x * inv); o.y = f2h(e.y * inv);
    o.z = f2h(e.z * inv); o.w = f2h(e.w * inv);
    *(ushort4*)&attn16[(size_t)row * C1 + lane * 4] = o;
}

// ---------------------------------------------------------------------------
// out[b][c][n] = x[b][c][n] + sum_d attn[c][d] * y[d][n]  via fp16 MFMA.
// A = attn16 [b][c][d] (k=d contiguous); B = yhiT CHUNKED [b][d/16][n][16d].
// Block tile 64c x 128n, 4 waves of 32x64. K-chunks of 64 (4 chunks).
// XCD swizzle: logical-consecutive blocks share attn16 (across x) and
// yhiT (across y) panels within an XCD.
// grid: (32, 4, 16)
// ---------------------------------------------------------------------------
__global__ __launch_bounds__(256) void out_mfma_kernel(
    const unsigned short* __restrict__ attn16, const unsigned short* __restrict__ yhiT,
    const float* __restrict__ x, float* __restrict__ out)
{
    int bx, by, bz;
    xcd_remap(bx, by, bz);
    const int b  = bz;
    const int cB = by * 64;
    const int nB = bx * 128;
    const int tid  = threadIdx.x;
    const int wid  = tid >> 6;
    const int lane = tid & 63;
    const int ln   = lane & 15;
    const int q    = lane >> 4;
    const int wm   = wid >> 1, wn = wid & 1;

    __shared__ unsigned short As[64 * 64];    //  8 KB, XOR-swizzled
    __shared__ unsigned short Bs[4 * 128 * 16];   // 16 KB: [u(4 d-sub)][128 n][16d]

    const int r8 = lane >> 3;
    const int gq = (lane & 7) ^ r8;

    f32x4 acc[2][4] = {};

    for (int ck = 0; ck < 4; ck++) {
        const int d0 = ck * 64;
        for (int it = wid; it < 24; it += 4) {
            if (it < 8) {
                const unsigned short* g =
                    attn16 + ((size_t)b * 256 + cB + it * 8 + r8) * 256 + d0 + gq * 8;
                GLDS(g, As + it * 512);
            } else {
                int j = it - 8;            // 0..15
                int u = j >> 2, part = j & 3;
                const unsigned short* g =
                    yhiT + (((size_t)b * 16 + ck * 4 + u) * 4096 + nB + part * 32) * 16 + lane * 8;
                GLDS(g, Bs + (u * 128 + part * 32) * 16);
            }
        }
        __syncthreads();

#pragma unroll
        for (int kwin = 0; kwin < 2; kwin++) {
            const int cc = (((kwin * 4 + q) ^ (ln & 7))) * 8;
            const int gK = kwin * 4 + q;
            half8 af[2], bfr[4];
#pragma unroll
            for (int mi = 0; mi < 2; mi++)
                af[mi] = *(const half8*)&As[(wm * 32 + mi * 16 + ln) * 64 + cc];
#pragma unroll
            for (int ni = 0; ni < 4; ni++) {
                int row = wn * 64 + ni * 16 + ln;
                bfr[ni] = *(const half8*)&Bs[(gK >> 1) * 2048 + row * 16 + (gK & 1) * 8];
            }
#pragma unroll
            for (int mi = 0; mi < 2; mi++)
#pragma unroll
                for (int ni = 0; ni < 4; ni++)
                    acc[mi][ni] = __builtin_amdgcn_mfma_f32_16x16x32_f16(
                        af[mi], bfr[ni], acc[mi][ni], 0, 0, 0);
        }
        __syncthreads();
    }

#pragma unroll
    for (int mi = 0; mi < 2; mi++)
#pragma unroll
        for (int ni = 0; ni < 4; ni++) {
            f32x4 a = acc[mi][ni];
            float vals[4] = {a.x, a.y, a.z, a.w};
#pragma unroll
            for (int r = 0; r < 4; r++) {
                int c = cB + wm * 32 + mi * 16 + q * 4 + r;
                int n = nB + wn * 64 + ni * 16 + ln;
                size_t o = ((size_t)b * C1 + c) * NN + n;
                out[o] = x[o] + vals[r];
            }
        }
}

// ---------------------------------------------------------------------------
extern "C" void kernel_launch(void* const* d_in, const int* in_sizes, int n_in,
                              void* d_out, int out_size, void* d_ws, size_t ws_size,
                              hipStream_t stream)
{
    const float* x  = (const float*)d_in[0];
    const float* w1 = (const float*)d_in[1];
    const float* g1 = (const float*)d_in[2];
    const float* b1 = (const float*)d_in[3];
    const float* m1 = (const float*)d_in[4];
    const float* v1 = (const float*)d_in[5];
    const float* w2 = (const float*)d_in[6];
    const float* g2 = (const float*)d_in[7];
    const float* b2 = (const float*)d_in[8];
    const float* m2 = (const float*)d_in[9];
    const float* v2 = (const float*)d_in[10];
    float* out = (float*)d_out;

    // workspace (86.6 MB total):
    //  xh [17,301,504 us] -- dead after conv1, REUSED as y_hi [16,777,216 us]
    //  y1h [8,650,752 us] -- dead after conv2, REUSED as sc0+sc1 (fp32
    //    split-K partials, 2 x 1,048,576 floats) + attn16 (1,048,576 us)
    unsigned short* xh   = (unsigned short*)d_ws;
    unsigned short* y1h  = xh  + (size_t)17301504;
    unsigned short* wt1  = y1h + (size_t)8650752;
    unsigned short* wt2  = wt1 + (size_t)294912;
    unsigned short* yhiT = wt2 + (size_t)294912;
    unsigned short* yhi  = xh;                         // alias (xh dead)
    float*          sc   = (float*)y1h;                // alias (y1h dead)
    unsigned short* attn16 = (unsigned short*)(sc + 2097152);

    // pre-pass
    nchw_to_nhwc_f16<<<dim3(C1 / 64, 66, BB), 256, 0, stream>>>(x, xh, C1);
    pack_w_kernel<<<(9 * CHD * C1 + 255) / 256, 256, 0, stream>>>(w1, wt1, CHD, C1);
    pack_w_kernel<<<(9 * C1 * CHD + 255) / 256, 256, 0, stream>>>(w2, wt2, C1, CHD);
    zero_y1h_pads<<<256, 256, 0, stream>>>(y1h);

    // conv1: 256 -> 128, chunked fp16 NHWC out (padded rows)
    conv_mfma_kernel<<<dim3(CHD / 64, 8, BB), 512, 0, stream>>>(
        xh, wt1, g1, b1, m1, v1, y1h, nullptr, nullptr, C1, CHD);
    // conv2: 128 -> 256, y_hi NCHW + yhiT chunked NHWC (overwrites xh region)
    conv_mfma_kernel<<<dim3(C1 / 64, 8, BB), 512, 0, stream>>>(
        y1h, wt2, g2, b2, m2, v2, nullptr, yhi, yhiT, CHD, C1);

    // attention: split-K symmetric fp16 MFMA scores -> softmax(sum halves)
    // -> fp16 MFMA PV + residual
    scores_mfma_kernel<<<dim3(10, 2, BB), 256, 0, stream>>>(yhi, sc);
    softmax_kernel<<<dim3(BB * C1), 64, 0, stream>>>(sc, attn16);
    out_mfma_kernel<<<dim3(NN / 128, 4, BB), 256, 0, stream>>>(attn16, yhiT, x, out);
}